// Round 1
// baseline (416.030 us; speedup 1.0000x reference)
//
#include <hip/hip_runtime.h>
#include <hip/hip_cooperative_groups.h>
#include <math.h>

// Problem constants
#define BATCH 16
#define CIN 32
#define COUT 96
#define WH 64
#define IMG (WH*WH)              // 4096
#define NPIX (BATCH*IMG)         // 65536 per channel
#define YELEMS (BATCH*COUT*IMG)  // 6291456
#define NPART 256                // partials per channel: 16 b * 16 rowg
#define PWELEMS (3*9*32*32)      // 27648 packed bf16 weights
#define XTELEMS (BATCH*IMG*CIN)  // 2097152 bf16 transposed x

namespace coopg = cooperative_groups;

typedef __attribute__((ext_vector_type(8))) short short8;
typedef __attribute__((ext_vector_type(4))) float floatx4;

__device__ __forceinline__ unsigned short f2bf(float f) {
    union { float f; unsigned u; } v; v.f = f;
    unsigned r = v.u + 0x7FFFu + ((v.u >> 16) & 1u);  // RNE
    return (unsigned short)(r >> 16);
}
__device__ __forceinline__ float bf2f(unsigned short u) {
    union { unsigned u; float f; } v; v.u = (unsigned)u << 16; return v.f;
}

#define GLDS(src, dst) __builtin_amdgcn_global_load_lds( \
    (const __attribute__((address_space(1))) void*)(src), \
    (__attribute__((address_space(3))) void*)(dst), 16, 0, 0)

__device__ __forceinline__ float fast_tanh(float xv) {
    float e = __expf(2.0f * xv);
    return fmaf(-2.0f, __builtin_amdgcn_rcpf(e + 1.0f), 1.0f);
}

// ---------------------------------------------------------------------------
// Fused cooperative kernel: grid = 768 blocks x 256 threads, exactly 3/CU.
// Phase A: transpose x -> xT bf16 (512 blocks), pack weights -> pw (108 blks)
// Phase B: implicit-GEMM conv (MFMA 16x16x32 bf16); y kept PACKED IN VGPRS
//          (16 regs/thread); per-block partial stats -> psum/psq
// Phase C: every block reduces the 256 partials for its 32 channels (L2 hits)
// Phase D: BN + tanh from registers, write fp32 out. No y materialization.
// ---------------------------------------------------------------------------
__global__ __launch_bounds__(256, 3) void fused_kernel(
    const float* __restrict__ x, const float* __restrict__ w,
    unsigned short* __restrict__ xT, unsigned short* __restrict__ pw,
    float* __restrict__ psum, float* __restrict__ psq,
    const float* __restrict__ gamma, const float* __restrict__ beta,
    float* __restrict__ out)
{
    // 10 rows (i0-3 .. i0+6, circular) x 64 cols x 32 ch bf16 = 40 KB
    __shared__ __align__(16) unsigned short tile[10 * 2048];
    __shared__ float red_s[4][32];
    __shared__ float red_q[4][32];
    __shared__ float sc_a[32];
    __shared__ float sc_b[32];

    int t   = threadIdx.x;
    int gid = blockIdx.x * 256 + t;

    // ---- Phase A: transpose (half-jobs: 16 ch of one (b,pix)) + weight pack
    if (gid < 2 * NPIX) {                 // 131072 half-jobs over 512 blocks
        int pt   = gid >> 1;              // b*4096 + pix
        int half = gid & 1;
        int b    = pt >> 12;
        int pix  = pt & 4095;
        const float* xb = x + ((size_t)b * CIN + half * 16) * IMG + pix;
        unsigned packed[8];
#pragma unroll
        for (int c2 = 0; c2 < 8; c2++) {
            unsigned short lo = f2bf(xb[(size_t)(2 * c2) * IMG]);
            unsigned short hi = f2bf(xb[(size_t)(2 * c2 + 1) * IMG]);
            packed[c2] = (unsigned)lo | ((unsigned)hi << 16);
        }
        uint4* dst = (uint4*)(xT + (size_t)pt * 32 + half * 16);
        dst[0] = make_uint4(packed[0], packed[1], packed[2], packed[3]);
        dst[1] = make_uint4(packed[4], packed[5], packed[6], packed[7]);
    } else if (gid < 2 * NPIX + PWELEMS) {
        int e   = gid - 2 * NPIX;
        int cfg = e / (9 * 1024);
        int rem = e % (9 * 1024);
        int tap = rem >> 10;
        int oc  = (rem >> 5) & 31;
        int c   = rem & 31;
        int dd  = cfg + 1;
        int du  = tap / 3, dv = tap % 3;
        size_t idx = (((size_t)(cfg * 32 + oc) * CIN + c) * 65 + (32 + (du - 1) * dd)) * 65
                     + (32 + (dv - 1) * dd);
        pw[e] = f2bf(w[idx]);
    }
    __threadfence();
    coopg::this_grid().sync();

    // ---- Phase B: conv. Block: 32 oc x 4 rows x 64 cols.
    int bid  = blockIdx.x;
    int rowg = bid & 15;
    int rest = bid >> 4;                 // 0..47
    int cfg  = rest % 3;
    int b    = rest / 3;
    int d    = cfg + 1;
    int i0   = rowg * 4;

    int wv   = t >> 6;
    int lane = t & 63;
    int l15  = lane & 15;
    int quad = lane >> 4;

    const unsigned short* xTb = xT + (size_t)b * IMG * 32;
#pragma unroll
    for (int rr = 0; rr < 10; rr++) {
        int gi = (i0 - 3 + rr) & 63;
        GLDS(xTb + (size_t)gi * 2048 + t * 8, &tile[rr * 2048 + t * 8]);
    }

    const unsigned short* pwc = pw + (size_t)cfg * 9 * 32 * 32;
    short8 af[2][9];
#pragma unroll
    for (int h = 0; h < 2; h++)
#pragma unroll
        for (int tap = 0; tap < 9; tap++)
            af[h][tap] = *(const short8*)(pwc + ((tap * 32 + h * 16 + l15) * 32 + quad * 8));

    __syncthreads();  // drains GLDS (vmcnt) for all waves

    float ss[2][4], qq[2][4];
#pragma unroll
    for (int h = 0; h < 2; h++)
#pragma unroll
        for (int r = 0; r < 4; r++) { ss[h][r] = 0.f; qq[h][r] = 0.f; }

    // y kept in regs: ypk[h][r][g] = bf16(cg=2g) | bf16(cg=2g+1)<<16
    unsigned ypk[2][4][2];
    int row = i0 + wv;

#pragma unroll
    for (int cgi = 0; cgi < 4; cgi++) {
        floatx4 a0 = {0.f, 0.f, 0.f, 0.f};
        floatx4 a1 = {0.f, 0.f, 0.f, 0.f};
#pragma unroll
        for (int du = 0; du < 3; du++) {
            int rowloc = wv + 3 + (du - 1) * d;        // 0..9
            const unsigned short* rbase = &tile[rowloc * 2048 + quad * 8];
#pragma unroll
            for (int dv = 0; dv < 3; dv++) {
                int col = (cgi * 16 + l15 + (dv - 1) * d) & 63;
                short8 bf = *(const short8*)(rbase + col * 32);
                a0 = __builtin_amdgcn_mfma_f32_16x16x32_bf16(af[0][du * 3 + dv], bf, a0, 0, 0, 0);
                a1 = __builtin_amdgcn_mfma_f32_16x16x32_bf16(af[1][du * 3 + dv], bf, a1, 0, 0, 0);
            }
        }
#pragma unroll
        for (int r = 0; r < 4; r++) {
            float v0 = a0[r], v1 = a1[r];
            unsigned short h0 = f2bf(v0), h1 = f2bf(v1);
            if (cgi & 1) {
                ypk[0][r][cgi >> 1] |= (unsigned)h0 << 16;
                ypk[1][r][cgi >> 1] |= (unsigned)h1 << 16;
            } else {
                ypk[0][r][cgi >> 1] = (unsigned)h0;
                ypk[1][r][cgi >> 1] = (unsigned)h1;
            }
            ss[0][r] += v0; qq[0][r] = fmaf(v0, v0, qq[0][r]);
            ss[1][r] += v1; qq[1][r] = fmaf(v1, v1, qq[1][r]);
        }
    }

    // reduce over the 16 column-lanes -> per-oc row sums
#pragma unroll
    for (int h = 0; h < 2; h++)
#pragma unroll
        for (int r = 0; r < 4; r++) {
            float s = ss[h][r], q = qq[h][r];
            for (int m = 1; m < 16; m <<= 1) {
                s += __shfl_xor(s, m, 64);
                q += __shfl_xor(q, m, 64);
            }
            if (l15 == 0) {
                red_s[wv][h * 16 + quad * 4 + r] = s;
                red_q[wv][h * 16 + quad * 4 + r] = q;
            }
        }
    __syncthreads();
    if (t < 32) {
        float S = red_s[0][t] + red_s[1][t] + red_s[2][t] + red_s[3][t];
        psum[(size_t)(cfg * 32 + t) * NPART + b * 16 + rowg] = S;
    } else if (t < 64) {
        int o = t - 32;
        float Q = red_q[0][o] + red_q[1][o] + red_q[2][o] + red_q[3][o];
        psq[(size_t)(cfg * 32 + o) * NPART + b * 16 + rowg] = Q;
    }
    __threadfence();
    coopg::this_grid().sync();

    // ---- Phase C: per-channel scale/shift for this block's 32 channels.
    {
        int chl = t >> 3;        // 0..31
        int seg = t & 7;         // 0..7, 32 partials each
        const float* ps = psum + (size_t)(cfg * 32 + chl) * NPART + seg * 32;
        const float* pq = psq  + (size_t)(cfg * 32 + chl) * NPART + seg * 32;
        float S = 0.f, Q = 0.f;
#pragma unroll
        for (int k = 0; k < 32; k++) { S += ps[k]; Q += pq[k]; }
#pragma unroll
        for (int m = 1; m < 8; m <<= 1) {
            S += __shfl_xor(S, m, 64);
            Q += __shfl_xor(Q, m, 64);
        }
        if (seg == 0) {
            const float inv_n = 1.0f / (float)NPIX;
            float mean = S * inv_n;
            float var  = Q * inv_n - mean * mean;
            float a    = gamma[cfg * 32 + chl] * rsqrtf(var + 1e-5f);
            sc_a[chl] = a;
            sc_b[chl] = beta[cfg * 32 + chl] - mean * a;
        }
    }
    __syncthreads();

    // ---- Phase D: BN + tanh straight from registers -> fp32 out.
#pragma unroll
    for (int h = 0; h < 2; h++)
#pragma unroll
        for (int r = 0; r < 4; r++) {
            int m0  = quad * 4 + r;
            int chl = h * 16 + m0;
            float a  = sc_a[chl];
            float bb = sc_b[chl];
            float* obase = out + ((size_t)b * COUT + cfg * 32 + chl) * IMG
                               + (size_t)row * WH + l15;
#pragma unroll
            for (int g = 0; g < 2; g++) {
                unsigned pk = ypk[h][r][g];
                obase[(2 * g) * 16]     = fast_tanh(fmaf(bf2f((unsigned short)(pk & 0xffffu)), a, bb));
                obase[(2 * g + 1) * 16] = fast_tanh(fmaf(bf2f((unsigned short)(pk >> 16)), a, bb));
            }
        }
}

// ---------------------------------------------------------------------------
// Fallback path (previous verified 3-kernel pipeline), used only if the
// cooperative launch is rejected (e.g. capture-unsupported).
// ---------------------------------------------------------------------------
__global__ __launch_bounds__(256) void prep_kernel(
    const float* __restrict__ x, const float* __restrict__ w,
    unsigned short* __restrict__ xT, unsigned short* __restrict__ pw)
{
    int blk = blockIdx.x;
    if (blk < 256) {
        int t   = blk * 256 + threadIdx.x;
        int b   = t >> 12;
        int pix = t & 4095;
        const float* xb = x + (size_t)b * CIN * IMG + pix;
        unsigned packed[16];
#pragma unroll
        for (int c2 = 0; c2 < 16; c2++) {
            unsigned short lo = f2bf(xb[(size_t)(2 * c2) * IMG]);
            unsigned short hi = f2bf(xb[(size_t)(2 * c2 + 1) * IMG]);
            packed[c2] = (unsigned)lo | ((unsigned)hi << 16);
        }
        uint4* dst = (uint4*)(xT + (size_t)t * 32);
#pragma unroll
        for (int k = 0; k < 4; k++)
            dst[k] = make_uint4(packed[4 * k], packed[4 * k + 1],
                                packed[4 * k + 2], packed[4 * k + 3]);
    } else {
        int e = (blk - 256) * 256 + threadIdx.x;
        if (e >= PWELEMS) return;
        int cfg = e / (9 * 1024);
        int rem = e % (9 * 1024);
        int tap = rem >> 10;
        int oc  = (rem >> 5) & 31;
        int c   = rem & 31;
        int d   = cfg + 1;
        int du  = tap / 3, dv = tap % 3;
        size_t idx = (((size_t)(cfg * 32 + oc) * CIN + c) * 65 + (32 + (du - 1) * d)) * 65
                     + (32 + (dv - 1) * d);
        pw[e] = f2bf(w[idx]);
    }
}

__global__ __launch_bounds__(256, 3) void conv_stats_kernel(
    const unsigned short* __restrict__ xT, const unsigned short* __restrict__ pw,
    unsigned short* __restrict__ yb, float* __restrict__ psum, float* __restrict__ psq)
{
    int bid  = blockIdx.x;
    int rowg = bid & 15;
    int rest = bid >> 4;
    int cfg  = rest % 3;
    int b    = rest / 3;
    int d    = cfg + 1;
    int i0   = rowg * 4;

    int t    = threadIdx.x;
    int wv   = t >> 6;
    int lane = t & 63;
    int l15  = lane & 15;
    int quad = lane >> 4;

    __shared__ __align__(16) unsigned short tile[10 * 2048];
    __shared__ float red_s[4][32];
    __shared__ float red_q[4][32];

    const unsigned short* xTb = xT + (size_t)b * IMG * 32;
#pragma unroll
    for (int rr = 0; rr < 10; rr++) {
        int gi = (i0 - 3 + rr) & 63;
        GLDS(xTb + (size_t)gi * 2048 + t * 8, &tile[rr * 2048 + t * 8]);
    }

    const unsigned short* pwc = pw + (size_t)cfg * 9 * 32 * 32;
    short8 af[2][9];
#pragma unroll
    for (int h = 0; h < 2; h++)
#pragma unroll
        for (int tap = 0; tap < 9; tap++)
            af[h][tap] = *(const short8*)(pwc + ((tap * 32 + h * 16 + l15) * 32 + quad * 8));

    __syncthreads();

    float ss[2][4], qq[2][4];
#pragma unroll
    for (int h = 0; h < 2; h++)
#pragma unroll
        for (int r = 0; r < 4; r++) { ss[h][r] = 0.f; qq[h][r] = 0.f; }

    int row = i0 + wv;
    size_t ybase = ((size_t)b * COUT + cfg * 32) * IMG + (size_t)row * WH;

#pragma unroll 1
    for (int cg = 0; cg < 4; cg++) {
        floatx4 a0 = {0.f, 0.f, 0.f, 0.f};
        floatx4 a1 = {0.f, 0.f, 0.f, 0.f};
#pragma unroll
        for (int du = 0; du < 3; du++) {
            int rowloc = wv + 3 + (du - 1) * d;
            const unsigned short* rbase = &tile[rowloc * 2048 + quad * 8];
#pragma unroll
            for (int dv = 0; dv < 3; dv++) {
                int col = (cg * 16 + l15 + (dv - 1) * d) & 63;
                short8 bf = *(const short8*)(rbase + col * 32);
                a0 = __builtin_amdgcn_mfma_f32_16x16x32_bf16(af[0][du * 3 + dv], bf, a0, 0, 0, 0);
                a1 = __builtin_amdgcn_mfma_f32_16x16x32_bf16(af[1][du * 3 + dv], bf, a1, 0, 0, 0);
            }
        }
        int colg = cg * 16 + l15;
#pragma unroll
        for (int r = 0; r < 4; r++) {
            float v0 = a0[r], v1 = a1[r];
            int m0 = quad * 4 + r;
            yb[ybase + (size_t)m0 * IMG + colg]        = f2bf(v0);
            yb[ybase + (size_t)(16 + m0) * IMG + colg] = f2bf(v1);
            ss[0][r] += v0; qq[0][r] = fmaf(v0, v0, qq[0][r]);
            ss[1][r] += v1; qq[1][r] = fmaf(v1, v1, qq[1][r]);
        }
    }

#pragma unroll
    for (int h = 0; h < 2; h++)
#pragma unroll
        for (int r = 0; r < 4; r++) {
            float s = ss[h][r], q = qq[h][r];
            for (int m = 1; m < 16; m <<= 1) {
                s += __shfl_xor(s, m, 64);
                q += __shfl_xor(q, m, 64);
            }
            if (l15 == 0) {
                red_s[wv][h * 16 + quad * 4 + r] = s;
                red_q[wv][h * 16 + quad * 4 + r] = q;
            }
        }
    __syncthreads();
    if (t < 32) {
        float S = red_s[0][t] + red_s[1][t] + red_s[2][t] + red_s[3][t];
        psum[(size_t)(cfg * 32 + t) * NPART + b * 16 + rowg] = S;
    } else if (t < 64) {
        int o = t - 32;
        float Q = red_q[0][o] + red_q[1][o] + red_q[2][o] + red_q[3][o];
        psq[(size_t)(cfg * 32 + o) * NPART + b * 16 + rowg] = Q;
    }
}

__global__ __launch_bounds__(256) void bn_tanh_kernel(
    const unsigned short* __restrict__ yb, const float* __restrict__ psum,
    const float* __restrict__ psq, const float* __restrict__ gamma,
    const float* __restrict__ beta, float* __restrict__ out)
{
    __shared__ float part[8];
    __shared__ float sc[2];
    int t  = threadIdx.x;
    int ch = blockIdx.x % COUT;

    float s = psum[(size_t)ch * NPART + t];
    float q = psq[(size_t)ch * NPART + t];
    for (int m = 1; m < 64; m <<= 1) {
        s += __shfl_xor(s, m, 64);
        q += __shfl_xor(q, m, 64);
    }
    if ((t & 63) == 0) { part[t >> 6] = s; part[4 + (t >> 6)] = q; }
    __syncthreads();
    if (t == 0) {
        const float inv_n = 1.0f / (float)NPIX;
        float S = part[0] + part[1] + part[2] + part[3];
        float Q = part[4] + part[5] + part[6] + part[7];
        float mean = S * inv_n;
        float var  = Q * inv_n - mean * mean;
        float a    = gamma[ch] * rsqrtf(var + 1e-5f);
        sc[0] = a;
        sc[1] = beta[ch] - mean * a;
    }
    __syncthreads();

    float a = sc[0], bsh = sc[1];
    size_t base = (size_t)blockIdx.x * IMG;
#pragma unroll
    for (int k = 0; k < 2; k++) {
        size_t off = base + k * 2048 + t * 8;
        uint4 raw = *(const uint4*)(yb + off);
        const unsigned short* u = (const unsigned short*)&raw;
        float4 r0, r1;
        r0.x = fast_tanh(fmaf(bf2f(u[0]), a, bsh));
        r0.y = fast_tanh(fmaf(bf2f(u[1]), a, bsh));
        r0.z = fast_tanh(fmaf(bf2f(u[2]), a, bsh));
        r0.w = fast_tanh(fmaf(bf2f(u[3]), a, bsh));
        r1.x = fast_tanh(fmaf(bf2f(u[4]), a, bsh));
        r1.y = fast_tanh(fmaf(bf2f(u[5]), a, bsh));
        r1.z = fast_tanh(fmaf(bf2f(u[6]), a, bsh));
        r1.w = fast_tanh(fmaf(bf2f(u[7]), a, bsh));
        *(float4*)(out + off)     = r0;
        *(float4*)(out + off + 4) = r1;
    }
}

extern "C" void kernel_launch(void* const* d_in, const int* in_sizes, int n_in,
                              void* d_out, int out_size, void* d_ws, size_t ws_size,
                              hipStream_t stream) {
    const float* x     = (const float*)d_in[0];
    const float* w     = (const float*)d_in[1];
    // d_in[2] = mask: tap positions known analytically (3x3 dilated, centered at 32)
    const float* gamma = (const float*)d_in[3];
    const float* beta  = (const float*)d_in[4];
    float* out = (float*)d_out;

    // transient state in d_ws — no d_out aliasing anywhere
    unsigned short* xT = (unsigned short*)d_ws;             // 2097152 bf16 (4 MB)
    unsigned short* pw = xT + XTELEMS;                      // 27648 bf16
    unsigned short* yb = pw + PWELEMS + 32;                 // fallback only
    float* psum = (float*)(yb + YELEMS);                    // 96*256
    float* psq  = psum + COUT * NPART;                      // 96*256

    void* args[] = {(void*)&x, (void*)&w, (void*)&xT, (void*)&pw,
                    (void*)&psum, (void*)&psq, (void*)&gamma, (void*)&beta,
                    (void*)&out};
    hipError_t err = hipLaunchCooperativeKernel((const void*)fused_kernel,
                                                dim3(768), dim3(256),
                                                args, 0, stream);
    if (err != hipSuccess) {
        // cooperative launch unavailable — previous verified 3-kernel path
        prep_kernel<<<256 + (PWELEMS + 255) / 256, 256, 0, stream>>>(x, w, xT, pw);
        conv_stats_kernel<<<768, 256, 0, stream>>>(xT, pw, yb, psum, psq);
        bn_tanh_kernel<<<BATCH * COUT, 256, 0, stream>>>(yb, psum, psq, gamma, beta, out);
    }
}

// Round 2
// 134.920 us; speedup vs baseline: 3.0835x; 3.0835x over previous
//
#include <hip/hip_runtime.h>
#include <math.h>

// Problem constants
#define BATCH 16
#define CIN 32
#define COUT 96
#define WH 64
#define IMG (WH*WH)              // 4096
#define NPIX (BATCH*IMG)         // 65536 per channel
#define PWELEMS (3*9*32*32)      // 27648 packed bf16 weights
#define XTELEMS (BATCH*IMG*CIN)  // 2097152 bf16 transposed x
#define NBLK 768                 // conv grid: 16 b * 3 cfg * 16 rowg

typedef __attribute__((ext_vector_type(8))) short short8;
typedef __attribute__((ext_vector_type(4))) float floatx4;

__device__ __forceinline__ unsigned short f2bf(float f) {
    union { float f; unsigned u; } v; v.f = f;
    unsigned r = v.u + 0x7FFFu + ((v.u >> 16) & 1u);  // RNE
    return (unsigned short)(r >> 16);
}
__device__ __forceinline__ float bf2f(unsigned short u) {
    union { unsigned u; float f; } v; v.u = (unsigned)u << 16; return v.f;
}

#define GLDS(src, dst) __builtin_amdgcn_global_load_lds( \
    (const __attribute__((address_space(1))) void*)(src), \
    (__attribute__((address_space(3))) void*)(dst), 16, 0, 0)

__device__ __forceinline__ float fast_tanh(float xv) {
    float e = __expf(2.0f * xv);
    return fmaf(-2.0f, __builtin_amdgcn_rcpf(e + 1.0f), 1.0f);
}

// ---------------------------------------------------------------------------
// prep: blocks 0..255 transpose x -> xT[b][pix][c] bf16 ; blocks 256..363 pack
// weights -> pw[cfg][tap][oc32][c32] bf16 ; block 364 zeroes the BN stat
// accumulators + barrier counter (workspace is poisoned each iteration).
// ---------------------------------------------------------------------------
__global__ __launch_bounds__(256) void prep_kernel(
    const float* __restrict__ x, const float* __restrict__ w,
    unsigned short* __restrict__ xT, unsigned short* __restrict__ pw,
    float* __restrict__ gsum, float* __restrict__ gsq,
    unsigned* __restrict__ cnt)
{
    int blk = blockIdx.x;
    if (blk < 256) {
        int t   = blk * 256 + threadIdx.x;   // 65536 = 16 b * 4096 pix
        int b   = t >> 12;
        int pix = t & 4095;
        const float* xb = x + (size_t)b * CIN * IMG + pix;
        unsigned packed[16];
#pragma unroll
        for (int c2 = 0; c2 < 16; c2++) {
            unsigned short lo = f2bf(xb[(size_t)(2 * c2) * IMG]);
            unsigned short hi = f2bf(xb[(size_t)(2 * c2 + 1) * IMG]);
            packed[c2] = (unsigned)lo | ((unsigned)hi << 16);
        }
        uint4* dst = (uint4*)(xT + (size_t)t * 32);
#pragma unroll
        for (int k = 0; k < 4; k++)
            dst[k] = make_uint4(packed[4 * k], packed[4 * k + 1],
                                packed[4 * k + 2], packed[4 * k + 3]);
    } else if (blk < 364) {
        int e = (blk - 256) * 256 + threadIdx.x;
        if (e >= PWELEMS) return;
        int cfg = e / (9 * 1024);
        int rem = e % (9 * 1024);
        int tap = rem >> 10;
        int oc  = (rem >> 5) & 31;
        int c   = rem & 31;
        int d   = cfg + 1;
        int du  = tap / 3, dv = tap % 3;
        size_t idx = (((size_t)(cfg * 32 + oc) * CIN + c) * 65 + (32 + (du - 1) * d)) * 65
                     + (32 + (dv - 1) * d);
        pw[e] = f2bf(w[idx]);
    } else {
        int e = threadIdx.x;
        if (e < COUT) { gsum[e] = 0.f; gsq[e] = 0.f; }
        if (e == COUT) *cnt = 0u;
    }
}

// ---------------------------------------------------------------------------
// Fused conv + BN + tanh. grid = 768 = 256 CU x 3 blocks/CU (all resident by
// __launch_bounds__(256,3): LDS 3*42.5KB=127.5 <= 160KB, VGPR ~70 <= 170).
// Phase B: implicit-GEMM conv (MFMA 16x16x32 bf16), y PACKED IN VGPRS
//          (16 regs/thread). Per-block stats accumulated via device-scope
//          atomicAdd -> LLC (coherent across XCDs, NO L2 flush needed).
// Barrier: one release fetch_add + relaxed agent-scope spin, thread 0 only.
//          Nothing else crosses XCDs (y in regs), so no acquire fence needed.
// Phase D: BN + tanh from registers, write fp32 out.
// ---------------------------------------------------------------------------
__global__ __launch_bounds__(256, 3) void conv_bn_kernel(
    const unsigned short* __restrict__ xT, const unsigned short* __restrict__ pw,
    float* __restrict__ gsum, float* __restrict__ gsq,
    unsigned* __restrict__ cnt,
    const float* __restrict__ gamma, const float* __restrict__ beta,
    float* __restrict__ out)
{
    // 10 rows (i0-3 .. i0+6, circular) x 64 cols x 32 ch bf16 = 40 KB
    __shared__ __align__(16) unsigned short tile[10 * 2048];
    __shared__ float red_s[4][32];
    __shared__ float red_q[4][32];
    __shared__ float sc_a[32];
    __shared__ float sc_b[32];

    int bid  = blockIdx.x;
    int rowg = bid & 15;
    int rest = bid >> 4;                 // 0..47
    int cfg  = rest % 3;
    int b    = rest / 3;
    int d    = cfg + 1;
    int i0   = rowg * 4;

    int t    = threadIdx.x;
    int wv   = t >> 6;
    int lane = t & 63;
    int l15  = lane & 15;
    int quad = lane >> 4;

    const unsigned short* xTb = xT + (size_t)b * IMG * 32;
#pragma unroll
    for (int rr = 0; rr < 10; rr++) {
        int gi = (i0 - 3 + rr) & 63;
        GLDS(xTb + (size_t)gi * 2048 + t * 8, &tile[rr * 2048 + t * 8]);
    }

    const unsigned short* pwc = pw + (size_t)cfg * 9 * 32 * 32;
    short8 af[2][9];
#pragma unroll
    for (int h = 0; h < 2; h++)
#pragma unroll
        for (int tap = 0; tap < 9; tap++)
            af[h][tap] = *(const short8*)(pwc + ((tap * 32 + h * 16 + l15) * 32 + quad * 8));

    __syncthreads();  // drains GLDS (vmcnt) for all waves

    float ss[2][4], qq[2][4];
#pragma unroll
    for (int h = 0; h < 2; h++)
#pragma unroll
        for (int r = 0; r < 4; r++) { ss[h][r] = 0.f; qq[h][r] = 0.f; }

    // y kept in regs: ypk[h][r][g] = bf16(cg=2g) | bf16(cg=2g+1)<<16
    unsigned ypk[2][4][2];
    int row = i0 + wv;

#pragma unroll
    for (int cgi = 0; cgi < 4; cgi++) {
        floatx4 a0 = {0.f, 0.f, 0.f, 0.f};
        floatx4 a1 = {0.f, 0.f, 0.f, 0.f};
#pragma unroll
        for (int du = 0; du < 3; du++) {
            int rowloc = wv + 3 + (du - 1) * d;        // 0..9
            const unsigned short* rbase = &tile[rowloc * 2048 + quad * 8];
#pragma unroll
            for (int dv = 0; dv < 3; dv++) {
                int col = (cgi * 16 + l15 + (dv - 1) * d) & 63;
                short8 bf = *(const short8*)(rbase + col * 32);
                a0 = __builtin_amdgcn_mfma_f32_16x16x32_bf16(af[0][du * 3 + dv], bf, a0, 0, 0, 0);
                a1 = __builtin_amdgcn_mfma_f32_16x16x32_bf16(af[1][du * 3 + dv], bf, a1, 0, 0, 0);
            }
        }
#pragma unroll
        for (int r = 0; r < 4; r++) {
            float v0 = a0[r], v1 = a1[r];
            unsigned short h0 = f2bf(v0), h1 = f2bf(v1);
            if (cgi & 1) {
                ypk[0][r][cgi >> 1] |= (unsigned)h0 << 16;
                ypk[1][r][cgi >> 1] |= (unsigned)h1 << 16;
            } else {
                ypk[0][r][cgi >> 1] = (unsigned)h0;
                ypk[1][r][cgi >> 1] = (unsigned)h1;
            }
            ss[0][r] += v0; qq[0][r] = fmaf(v0, v0, qq[0][r]);
            ss[1][r] += v1; qq[1][r] = fmaf(v1, v1, qq[1][r]);
        }
    }

    // reduce over the 16 column-lanes -> per-oc row sums
#pragma unroll
    for (int h = 0; h < 2; h++)
#pragma unroll
        for (int r = 0; r < 4; r++) {
            float s = ss[h][r], q = qq[h][r];
            for (int m = 1; m < 16; m <<= 1) {
                s += __shfl_xor(s, m, 64);
                q += __shfl_xor(q, m, 64);
            }
            if (l15 == 0) {
                red_s[wv][h * 16 + quad * 4 + r] = s;
                red_q[wv][h * 16 + quad * 4 + r] = q;
            }
        }
    __syncthreads();

    // one atomicAdd per (block, channel): device-scope -> LLC, XCD-coherent
    if (t < 32) {
        float S = red_s[0][t] + red_s[1][t] + red_s[2][t] + red_s[3][t];
        atomicAdd(&gsum[cfg * 32 + t], S);
    } else if (t < 64) {
        int o = t - 32;
        float Q = red_q[0][o] + red_q[1][o] + red_q[2][o] + red_q[3][o];
        atomicAdd(&gsq[cfg * 32 + o], Q);
    }
    __syncthreads();   // all 4 waves' atomics drained (vmcnt 0) before arrive

    // ---- lightweight grid barrier: no per-wave fences, no L2 flush storm
    if (t == 0) {
        __hip_atomic_fetch_add(cnt, 1u, __ATOMIC_RELEASE, __HIP_MEMORY_SCOPE_AGENT);
        while (__hip_atomic_load(cnt, __ATOMIC_RELAXED, __HIP_MEMORY_SCOPE_AGENT) < NBLK)
            __builtin_amdgcn_s_sleep(8);
    }
    __syncthreads();

    // ---- per-channel scale/shift (atomic loads: coherent at LLC)
    if (t < 32) {
        int ch = cfg * 32 + t;
        float S = __hip_atomic_load(&gsum[ch], __ATOMIC_RELAXED, __HIP_MEMORY_SCOPE_AGENT);
        float Q = __hip_atomic_load(&gsq[ch],  __ATOMIC_RELAXED, __HIP_MEMORY_SCOPE_AGENT);
        const float inv_n = 1.0f / (float)NPIX;
        float mean = S * inv_n;
        float var  = Q * inv_n - mean * mean;
        float a    = gamma[ch] * rsqrtf(var + 1e-5f);
        sc_a[t] = a;
        sc_b[t] = beta[ch] - mean * a;
    }
    __syncthreads();

    // ---- Phase D: BN + tanh straight from registers -> fp32 out.
#pragma unroll
    for (int h = 0; h < 2; h++)
#pragma unroll
        for (int r = 0; r < 4; r++) {
            int m0  = quad * 4 + r;
            int chl = h * 16 + m0;
            float a  = sc_a[chl];
            float bb = sc_b[chl];
            float* obase = out + ((size_t)b * COUT + cfg * 32 + chl) * IMG
                               + (size_t)row * WH + l15;
#pragma unroll
            for (int g = 0; g < 2; g++) {
                unsigned pk = ypk[h][r][g];
                obase[(2 * g) * 16]     = fast_tanh(fmaf(bf2f((unsigned short)(pk & 0xffffu)), a, bb));
                obase[(2 * g + 1) * 16] = fast_tanh(fmaf(bf2f((unsigned short)(pk >> 16)), a, bb));
            }
        }
}

extern "C" void kernel_launch(void* const* d_in, const int* in_sizes, int n_in,
                              void* d_out, int out_size, void* d_ws, size_t ws_size,
                              hipStream_t stream) {
    const float* x     = (const float*)d_in[0];
    const float* w     = (const float*)d_in[1];
    // d_in[2] = mask: tap positions known analytically (3x3 dilated, centered at 32)
    const float* gamma = (const float*)d_in[3];
    const float* beta  = (const float*)d_in[4];
    float* out = (float*)d_out;

    // transient state in d_ws — no d_out aliasing anywhere
    unsigned short* xT = (unsigned short*)d_ws;             // 2097152 bf16 (4 MB)
    unsigned short* pw = xT + XTELEMS;                      // 27648 bf16
    float* gsum = (float*)(pw + PWELEMS + 32);              // 96 floats
    float* gsq  = gsum + 128;                               // 96 floats (padded)
    unsigned* cnt = (unsigned*)(gsq + 128);                 // barrier counter

    prep_kernel<<<365, 256, 0, stream>>>(x, w, xT, pw, gsum, gsq, cnt);
    conv_bn_kernel<<<NBLK, 256, 0, stream>>>(xT, pw, gsum, gsq, cnt,
                                             gamma, beta, out);
}

// Round 3
// 123.217 us; speedup vs baseline: 3.3764x; 1.0950x over previous
//
#include <hip/hip_runtime.h>
#include <math.h>

// Problem constants
#define BATCH 16
#define CIN 32
#define COUT 96
#define WH 64
#define IMG (WH*WH)              // 4096
#define NPIX (BATCH*IMG)         // 65536 per channel
#define PWELEMS (3*9*32*32)      // 27648 packed bf16 weights
#define XTELEMS (BATCH*IMG*CIN)  // 2097152 bf16 transposed x
#define NBLK 768                 // conv grid: 16 b * 3 cfg * 16 rowg

typedef __attribute__((ext_vector_type(8))) short short8;
typedef __attribute__((ext_vector_type(4))) float floatx4;

__device__ __forceinline__ unsigned short f2bf(float f) {
    union { float f; unsigned u; } v; v.f = f;
    unsigned r = v.u + 0x7FFFu + ((v.u >> 16) & 1u);  // RNE
    return (unsigned short)(r >> 16);
}
__device__ __forceinline__ float bf2f(unsigned short u) {
    union { unsigned u; float f; } v; v.u = (unsigned)u << 16; return v.f;
}

#define GLDS(src, dst) __builtin_amdgcn_global_load_lds( \
    (const __attribute__((address_space(1))) void*)(src), \
    (__attribute__((address_space(3))) void*)(dst), 16, 0, 0)

__device__ __forceinline__ float fast_tanh(float xv) {
    float e = __expf(2.0f * xv);
    return fmaf(-2.0f, __builtin_amdgcn_rcpf(e + 1.0f), 1.0f);
}

// ---------------------------------------------------------------------------
// prep: blocks 0..511 transpose x -> xT[b][pix][c] bf16 (half-jobs: 16 ch of
// one (b,pix) each) ; blocks 512..619 pack weights -> pw[cfg][tap][oc][c] ;
// block 620 zeroes BN accumulators + barrier counter (ws is re-poisoned
// every iteration, so init must happen on-stream each launch).
// ---------------------------------------------------------------------------
__global__ __launch_bounds__(256) void prep_kernel(
    const float* __restrict__ x, const float* __restrict__ w,
    unsigned short* __restrict__ xT, unsigned short* __restrict__ pw,
    float* __restrict__ gsum, float* __restrict__ gsq,
    unsigned* __restrict__ cnt)
{
    int blk = blockIdx.x;
    if (blk < 512) {
        int gid  = blk * 256 + threadIdx.x;  // 131072 half-jobs
        int pt   = gid >> 1;                 // b*4096 + pix
        int half = gid & 1;
        int b    = pt >> 12;
        int pix  = pt & 4095;
        const float* xb = x + ((size_t)b * CIN + half * 16) * IMG + pix;
        unsigned packed[8];
#pragma unroll
        for (int c2 = 0; c2 < 8; c2++) {
            unsigned short lo = f2bf(xb[(size_t)(2 * c2) * IMG]);
            unsigned short hi = f2bf(xb[(size_t)(2 * c2 + 1) * IMG]);
            packed[c2] = (unsigned)lo | ((unsigned)hi << 16);
        }
        uint4* dst = (uint4*)(xT + (size_t)pt * 32 + half * 16);
        dst[0] = make_uint4(packed[0], packed[1], packed[2], packed[3]);
        dst[1] = make_uint4(packed[4], packed[5], packed[6], packed[7]);
    } else if (blk < 620) {
        int e = (blk - 512) * 256 + threadIdx.x;
        if (e >= PWELEMS) return;
        int cfg = e / (9 * 1024);
        int rem = e % (9 * 1024);
        int tap = rem >> 10;
        int oc  = (rem >> 5) & 31;
        int c   = rem & 31;
        int d   = cfg + 1;
        int du  = tap / 3, dv = tap % 3;
        size_t idx = (((size_t)(cfg * 32 + oc) * CIN + c) * 65 + (32 + (du - 1) * d)) * 65
                     + (32 + (dv - 1) * d);
        pw[e] = f2bf(w[idx]);
    } else {
        int e = threadIdx.x;
        if (e < COUT) { gsum[e] = 0.f; gsq[e] = 0.f; }
        if (e == COUT) *cnt = 0u;
    }
}

// ---------------------------------------------------------------------------
// Fused conv + BN + tanh. grid = 768 = 256 CU x 3 blocks/CU, all co-resident
// (__launch_bounds__(256,3): LDS 3*41.5KB=124.5 <= 160KB, VGPR 68).
// Phase B: implicit-GEMM conv (MFMA 16x16x32 bf16), y PACKED IN VGPRS.
// Stats: device-scope atomicAdd -> LLC (coherent across XCDs).
// Barrier: RELAXED fetch_add arrive + relaxed agent spin, thread 0 only.
//   All cross-XCD data (gsum/gsq/cnt) lives at the LLC coherence point and
//   the __syncthreads before arrive drains every wave's atomics (vmcnt), so
//   LLC serialization alone orders adds-before-arrive. RELAXED (not RELEASE)
//   is essential: agent-scope release lowers to buffer_wbl2 (full L2
//   writeback) per arrive -> the 30us idle measured in round 2.
// Phase D: BN + tanh from registers, write fp32 out.
// ---------------------------------------------------------------------------
__global__ __launch_bounds__(256, 3) void conv_bn_kernel(
    const unsigned short* __restrict__ xT, const unsigned short* __restrict__ pw,
    float* __restrict__ gsum, float* __restrict__ gsq,
    unsigned* __restrict__ cnt,
    const float* __restrict__ gamma, const float* __restrict__ beta,
    float* __restrict__ out)
{
    // 10 rows (i0-3 .. i0+6, circular) x 64 cols x 32 ch bf16 = 40 KB
    __shared__ __align__(16) unsigned short tile[10 * 2048];
    __shared__ float red_s[4][32];
    __shared__ float red_q[4][32];
    __shared__ float sc_a[32];
    __shared__ float sc_b[32];

    int bid  = blockIdx.x;
    int rowg = bid & 15;
    int rest = bid >> 4;                 // 0..47
    int cfg  = rest % 3;
    int b    = rest / 3;
    int d    = cfg + 1;
    int i0   = rowg * 4;

    int t    = threadIdx.x;
    int wv   = t >> 6;
    int lane = t & 63;
    int l15  = lane & 15;
    int quad = lane >> 4;

    const unsigned short* xTb = xT + (size_t)b * IMG * 32;
#pragma unroll
    for (int rr = 0; rr < 10; rr++) {
        int gi = (i0 - 3 + rr) & 63;
        GLDS(xTb + (size_t)gi * 2048 + t * 8, &tile[rr * 2048 + t * 8]);
    }

    const unsigned short* pwc = pw + (size_t)cfg * 9 * 32 * 32;
    short8 af[2][9];
#pragma unroll
    for (int h = 0; h < 2; h++)
#pragma unroll
        for (int tap = 0; tap < 9; tap++)
            af[h][tap] = *(const short8*)(pwc + ((tap * 32 + h * 16 + l15) * 32 + quad * 8));

    __syncthreads();  // drains GLDS (vmcnt) for all waves

    float ss[2][4], qq[2][4];
#pragma unroll
    for (int h = 0; h < 2; h++)
#pragma unroll
        for (int r = 0; r < 4; r++) { ss[h][r] = 0.f; qq[h][r] = 0.f; }

    // y kept in regs: ypk[h][r][g] = bf16(cg=2g) | bf16(cg=2g+1)<<16
    unsigned ypk[2][4][2];
    int row = i0 + wv;

#pragma unroll
    for (int cgi = 0; cgi < 4; cgi++) {
        floatx4 a0 = {0.f, 0.f, 0.f, 0.f};
        floatx4 a1 = {0.f, 0.f, 0.f, 0.f};
#pragma unroll
        for (int du = 0; du < 3; du++) {
            int rowloc = wv + 3 + (du - 1) * d;        // 0..9
            const unsigned short* rbase = &tile[rowloc * 2048 + quad * 8];
#pragma unroll
            for (int dv = 0; dv < 3; dv++) {
                int col = (cgi * 16 + l15 + (dv - 1) * d) & 63;
                short8 bf = *(const short8*)(rbase + col * 32);
                a0 = __builtin_amdgcn_mfma_f32_16x16x32_bf16(af[0][du * 3 + dv], bf, a0, 0, 0, 0);
                a1 = __builtin_amdgcn_mfma_f32_16x16x32_bf16(af[1][du * 3 + dv], bf, a1, 0, 0, 0);
            }
        }
#pragma unroll
        for (int r = 0; r < 4; r++) {
            float v0 = a0[r], v1 = a1[r];
            unsigned short h0 = f2bf(v0), h1 = f2bf(v1);
            if (cgi & 1) {
                ypk[0][r][cgi >> 1] |= (unsigned)h0 << 16;
                ypk[1][r][cgi >> 1] |= (unsigned)h1 << 16;
            } else {
                ypk[0][r][cgi >> 1] = (unsigned)h0;
                ypk[1][r][cgi >> 1] = (unsigned)h1;
            }
            ss[0][r] += v0; qq[0][r] = fmaf(v0, v0, qq[0][r]);
            ss[1][r] += v1; qq[1][r] = fmaf(v1, v1, qq[1][r]);
        }
    }

    // reduce over the 16 column-lanes -> per-oc row sums
#pragma unroll
    for (int h = 0; h < 2; h++)
#pragma unroll
        for (int r = 0; r < 4; r++) {
            float s = ss[h][r], q = qq[h][r];
            for (int m = 1; m < 16; m <<= 1) {
                s += __shfl_xor(s, m, 64);
                q += __shfl_xor(q, m, 64);
            }
            if (l15 == 0) {
                red_s[wv][h * 16 + quad * 4 + r] = s;
                red_q[wv][h * 16 + quad * 4 + r] = q;
            }
        }
    __syncthreads();

    // one atomicAdd per (block, channel): device-scope -> LLC, XCD-coherent
    if (t < 32) {
        float S = red_s[0][t] + red_s[1][t] + red_s[2][t] + red_s[3][t];
        atomicAdd(&gsum[cfg * 32 + t], S);
    } else if (t < 64) {
        int o = t - 32;
        float Q = red_q[0][o] + red_q[1][o] + red_q[2][o] + red_q[3][o];
        atomicAdd(&gsq[cfg * 32 + o], Q);
    }
    __syncthreads();   // all 4 waves' atomics completed (vmcnt 0) before arrive

    // ---- grid barrier: RELAXED arrive (no buffer_wbl2), relaxed spin
    if (t == 0) {
        __hip_atomic_fetch_add(cnt, 1u, __ATOMIC_RELAXED, __HIP_MEMORY_SCOPE_AGENT);
        while (__hip_atomic_load(cnt, __ATOMIC_RELAXED, __HIP_MEMORY_SCOPE_AGENT) < NBLK)
            __builtin_amdgcn_s_sleep(2);
    }
    __syncthreads();

    // ---- per-channel scale/shift (atomic loads: coherent at LLC)
    if (t < 32) {
        int ch = cfg * 32 + t;
        float S = __hip_atomic_load(&gsum[ch], __ATOMIC_RELAXED, __HIP_MEMORY_SCOPE_AGENT);
        float Q = __hip_atomic_load(&gsq[ch],  __ATOMIC_RELAXED, __HIP_MEMORY_SCOPE_AGENT);
        const float inv_n = 1.0f / (float)NPIX;
        float mean = S * inv_n;
        float var  = Q * inv_n - mean * mean;
        float a    = gamma[ch] * rsqrtf(var + 1e-5f);
        sc_a[t] = a;
        sc_b[t] = beta[ch] - mean * a;
    }
    __syncthreads();

    // ---- Phase D: BN + tanh straight from registers -> fp32 out.
#pragma unroll
    for (int h = 0; h < 2; h++)
#pragma unroll
        for (int r = 0; r < 4; r++) {
            int m0  = quad * 4 + r;
            int chl = h * 16 + m0;
            float a  = sc_a[chl];
            float bb = sc_b[chl];
            float* obase = out + ((size_t)b * COUT + cfg * 32 + chl) * IMG
                               + (size_t)row * WH + l15;
#pragma unroll
            for (int g = 0; g < 2; g++) {
                unsigned pk = ypk[h][r][g];
                obase[(2 * g) * 16]     = fast_tanh(fmaf(bf2f((unsigned short)(pk & 0xffffu)), a, bb));
                obase[(2 * g + 1) * 16] = fast_tanh(fmaf(bf2f((unsigned short)(pk >> 16)), a, bb));
            }
        }
}

extern "C" void kernel_launch(void* const* d_in, const int* in_sizes, int n_in,
                              void* d_out, int out_size, void* d_ws, size_t ws_size,
                              hipStream_t stream) {
    const float* x     = (const float*)d_in[0];
    const float* w     = (const float*)d_in[1];
    // d_in[2] = mask: tap positions known analytically (3x3 dilated, centered at 32)
    const float* gamma = (const float*)d_in[3];
    const float* beta  = (const float*)d_in[4];
    float* out = (float*)d_out;

    // transient state in d_ws — no d_out aliasing anywhere
    unsigned short* xT = (unsigned short*)d_ws;             // 2097152 bf16 (4 MB)
    unsigned short* pw = xT + XTELEMS;                      // 27648 bf16
    float* gsum = (float*)(pw + PWELEMS + 32);              // 96 floats
    float* gsq  = gsum + 128;                               // 96 floats (padded)
    unsigned* cnt = (unsigned*)(gsq + 128);                 // barrier counter

    prep_kernel<<<621, 256, 0, stream>>>(x, w, xT, pw, gsum, gsq, cnt);
    conv_bn_kernel<<<NBLK, 256, 0, stream>>>(xT, pw, gsum, gsq, cnt,
                                             gamma, beta, out);
}

// Round 4
// 116.041 us; speedup vs baseline: 3.5852x; 1.0618x over previous
//
#include <hip/hip_runtime.h>
#include <math.h>

// Problem constants
#define BATCH 16
#define CIN 32
#define COUT 96
#define WH 64
#define IMG (WH*WH)              // 4096
#define NPIX (BATCH*IMG)         // 65536 per channel
#define PWELEMS (3*9*32*32)      // 27648 packed bf16 weights
#define XTELEMS (BATCH*IMG*CIN)  // 2097152 bf16 transposed x
#define NBLK 768                 // conv grid: 16 b * 3 cfg * 16 rowg
#define NGRP 96                  // barrier groups of 8 blocks
#define PAD 16                   // one cacheline (64B) per counter/accumulator
// barrier/stat region: gsum[96*16] gsq[96*16] gcnt[96*16] ggo[96*16] groot[16]
#define ZWORDS (4*NGRP*PAD + PAD)

typedef __attribute__((ext_vector_type(8))) short short8;
typedef __attribute__((ext_vector_type(4))) float floatx4;

__device__ __forceinline__ unsigned short f2bf(float f) {
    union { float f; unsigned u; } v; v.f = f;
    unsigned r = v.u + 0x7FFFu + ((v.u >> 16) & 1u);  // RNE
    return (unsigned short)(r >> 16);
}
__device__ __forceinline__ float bf2f(unsigned short u) {
    union { unsigned u; float f; } v; v.u = (unsigned)u << 16; return v.f;
}

#define GLDS(src, dst) __builtin_amdgcn_global_load_lds( \
    (const __attribute__((address_space(1))) void*)(src), \
    (__attribute__((address_space(3))) void*)(dst), 16, 0, 0)

__device__ __forceinline__ float fast_tanh(float xv) {
    float e = __expf(2.0f * xv);
    return fmaf(-2.0f, __builtin_amdgcn_rcpf(e + 1.0f), 1.0f);
}

// ---------------------------------------------------------------------------
// prep: blocks 0..511 transpose x -> xT[b][pix][c] bf16 ; blocks 512..619
// pack weights -> pw ; block 620 zeroes the barrier/stat region (ws is
// re-poisoned every iteration). Kernel-boundary release makes zeros visible.
// ---------------------------------------------------------------------------
__global__ __launch_bounds__(256) void prep_kernel(
    const float* __restrict__ x, const float* __restrict__ w,
    unsigned short* __restrict__ xT, unsigned short* __restrict__ pw,
    unsigned* __restrict__ zbase)
{
    int blk = blockIdx.x;
    if (blk < 512) {
        int gid  = blk * 256 + threadIdx.x;  // 131072 half-jobs
        int pt   = gid >> 1;                 // b*4096 + pix
        int half = gid & 1;
        int b    = pt >> 12;
        int pix  = pt & 4095;
        const float* xb = x + ((size_t)b * CIN + half * 16) * IMG + pix;
        unsigned packed[8];
#pragma unroll
        for (int c2 = 0; c2 < 8; c2++) {
            unsigned short lo = f2bf(xb[(size_t)(2 * c2) * IMG]);
            unsigned short hi = f2bf(xb[(size_t)(2 * c2 + 1) * IMG]);
            packed[c2] = (unsigned)lo | ((unsigned)hi << 16);
        }
        uint4* dst = (uint4*)(xT + (size_t)pt * 32 + half * 16);
        dst[0] = make_uint4(packed[0], packed[1], packed[2], packed[3]);
        dst[1] = make_uint4(packed[4], packed[5], packed[6], packed[7]);
    } else if (blk < 620) {
        int e = (blk - 512) * 256 + threadIdx.x;
        if (e >= PWELEMS) return;
        int cfg = e / (9 * 1024);
        int rem = e % (9 * 1024);
        int tap = rem >> 10;
        int oc  = (rem >> 5) & 31;
        int c   = rem & 31;
        int d   = cfg + 1;
        int du  = tap / 3, dv = tap % 3;
        size_t idx = (((size_t)(cfg * 32 + oc) * CIN + c) * 65 + (32 + (du - 1) * d)) * 65
                     + (32 + (dv - 1) * d);
        pw[e] = f2bf(w[idx]);
    } else {
        for (int i = threadIdx.x; i < ZWORDS; i += 256) zbase[i] = 0u;
    }
}

// ---------------------------------------------------------------------------
// Fused conv + BN + tanh. grid = 768 = 256 CU x 3 blocks/CU, all co-resident
// (LDS 3*41.5KB=124.5 <= 160KB, VGPR ~70).
// Stats: per-channel accumulators PADDED to one cacheline each (96 lines,
//   256 RMWs/line spread across LLC slices — was 4096/line on 12 lines).
// Barrier: hierarchical. 96 group counters (own line each, 8 arrivals) ->
//   1 root counter (96 RMWs, nobody spins on it) -> 96 go-flag lines set by
//   the single root finisher. Members spin on their group's go line: <=8
//   spinners/line (was 767 spinners on ONE line -> LLC slice saturation,
//   the ~17us residual of round 3). All ops RELAXED agent-scope: everything
//   crossing XCDs lives at the LLC coherence point; no L2 writeback needed.
// ---------------------------------------------------------------------------
__global__ __launch_bounds__(256, 3) void conv_bn_kernel(
    const unsigned short* __restrict__ xT, const unsigned short* __restrict__ pw,
    float* __restrict__ gsum, float* __restrict__ gsq,
    unsigned* __restrict__ gcnt, unsigned* __restrict__ ggo,
    unsigned* __restrict__ groot,
    const float* __restrict__ gamma, const float* __restrict__ beta,
    float* __restrict__ out)
{
    // 10 rows (i0-3 .. i0+6, circular) x 64 cols x 32 ch bf16 = 40 KB
    __shared__ __align__(16) unsigned short tile[10 * 2048];
    __shared__ float red_s[4][32];
    __shared__ float red_q[4][32];
    __shared__ float sc_a[32];
    __shared__ float sc_b[32];

    int bid  = blockIdx.x;
    int rowg = bid & 15;
    int rest = bid >> 4;                 // 0..47
    int cfg  = rest % 3;
    int b    = rest / 3;
    int d    = cfg + 1;
    int i0   = rowg * 4;

    int t    = threadIdx.x;
    int wv   = t >> 6;
    int lane = t & 63;
    int l15  = lane & 15;
    int quad = lane >> 4;

    const unsigned short* xTb = xT + (size_t)b * IMG * 32;
#pragma unroll
    for (int rr = 0; rr < 10; rr++) {
        int gi = (i0 - 3 + rr) & 63;
        GLDS(xTb + (size_t)gi * 2048 + t * 8, &tile[rr * 2048 + t * 8]);
    }

    const unsigned short* pwc = pw + (size_t)cfg * 9 * 32 * 32;
    short8 af[2][9];
#pragma unroll
    for (int h = 0; h < 2; h++)
#pragma unroll
        for (int tap = 0; tap < 9; tap++)
            af[h][tap] = *(const short8*)(pwc + ((tap * 32 + h * 16 + l15) * 32 + quad * 8));

    // preload gamma/beta (shortens post-barrier critical path)
    float gam = 0.f, bet = 0.f;
    if (t < 32) { gam = gamma[cfg * 32 + t]; bet = beta[cfg * 32 + t]; }

    __syncthreads();  // drains GLDS (vmcnt) for all waves

    float ss[2][4], qq[2][4];
#pragma unroll
    for (int h = 0; h < 2; h++)
#pragma unroll
        for (int r = 0; r < 4; r++) { ss[h][r] = 0.f; qq[h][r] = 0.f; }

    // y kept in regs: ypk[h][r][g] = bf16(cg=2g) | bf16(cg=2g+1)<<16
    unsigned ypk[2][4][2];
    int row = i0 + wv;

#pragma unroll
    for (int cgi = 0; cgi < 4; cgi++) {
        floatx4 a0 = {0.f, 0.f, 0.f, 0.f};
        floatx4 a1 = {0.f, 0.f, 0.f, 0.f};
#pragma unroll
        for (int du = 0; du < 3; du++) {
            int rowloc = wv + 3 + (du - 1) * d;        // 0..9
            const unsigned short* rbase = &tile[rowloc * 2048 + quad * 8];
#pragma unroll
            for (int dv = 0; dv < 3; dv++) {
                int col = (cgi * 16 + l15 + (dv - 1) * d) & 63;
                short8 bf = *(const short8*)(rbase + col * 32);
                a0 = __builtin_amdgcn_mfma_f32_16x16x32_bf16(af[0][du * 3 + dv], bf, a0, 0, 0, 0);
                a1 = __builtin_amdgcn_mfma_f32_16x16x32_bf16(af[1][du * 3 + dv], bf, a1, 0, 0, 0);
            }
        }
#pragma unroll
        for (int r = 0; r < 4; r++) {
            float v0 = a0[r], v1 = a1[r];
            unsigned short h0 = f2bf(v0), h1 = f2bf(v1);
            if (cgi & 1) {
                ypk[0][r][cgi >> 1] |= (unsigned)h0 << 16;
                ypk[1][r][cgi >> 1] |= (unsigned)h1 << 16;
            } else {
                ypk[0][r][cgi >> 1] = (unsigned)h0;
                ypk[1][r][cgi >> 1] = (unsigned)h1;
            }
            ss[0][r] += v0; qq[0][r] = fmaf(v0, v0, qq[0][r]);
            ss[1][r] += v1; qq[1][r] = fmaf(v1, v1, qq[1][r]);
        }
    }

    // reduce over the 16 column-lanes -> per-oc row sums
#pragma unroll
    for (int h = 0; h < 2; h++)
#pragma unroll
        for (int r = 0; r < 4; r++) {
            float s = ss[h][r], q = qq[h][r];
            for (int m = 1; m < 16; m <<= 1) {
                s += __shfl_xor(s, m, 64);
                q += __shfl_xor(q, m, 64);
            }
            if (l15 == 0) {
                red_s[wv][h * 16 + quad * 4 + r] = s;
                red_q[wv][h * 16 + quad * 4 + r] = q;
            }
        }
    __syncthreads();

    // per-(block,channel) atomicAdd; each channel accumulator on its OWN line
    if (t < 32) {
        float S = red_s[0][t] + red_s[1][t] + red_s[2][t] + red_s[3][t];
        atomicAdd(&gsum[(cfg * 32 + t) * PAD], S);
    } else if (t < 64) {
        int o = t - 32;
        float Q = red_q[0][o] + red_q[1][o] + red_q[2][o] + red_q[3][o];
        atomicAdd(&gsq[(cfg * 32 + o) * PAD], Q);
    }
    __syncthreads();   // all waves' atomics completed (vmcnt 0) before arrive

    // ---- hierarchical grid barrier (all RELAXED, spread spin lines)
    if (t == 0) {
        int g = bid >> 3;
        unsigned r = __hip_atomic_fetch_add(&gcnt[g * PAD], 1u,
                                            __ATOMIC_RELAXED, __HIP_MEMORY_SCOPE_AGENT);
        if (r == 7u) {
            unsigned rr = __hip_atomic_fetch_add(groot, 1u,
                                                 __ATOMIC_RELAXED, __HIP_MEMORY_SCOPE_AGENT);
            if (rr == (unsigned)(NGRP - 1)) {
                for (int gg = 0; gg < NGRP; gg++)
                    __hip_atomic_store(&ggo[gg * PAD], 1u,
                                       __ATOMIC_RELAXED, __HIP_MEMORY_SCOPE_AGENT);
            }
        }
        while (__hip_atomic_load(&ggo[g * PAD], __ATOMIC_RELAXED,
                                 __HIP_MEMORY_SCOPE_AGENT) == 0u)
            __builtin_amdgcn_s_sleep(4);
    }
    __syncthreads();

    // ---- per-channel scale/shift (atomic loads: coherent at LLC)
    if (t < 32) {
        int ch = cfg * 32 + t;
        float S = __hip_atomic_load(&gsum[ch * PAD], __ATOMIC_RELAXED, __HIP_MEMORY_SCOPE_AGENT);
        float Q = __hip_atomic_load(&gsq[ch * PAD],  __ATOMIC_RELAXED, __HIP_MEMORY_SCOPE_AGENT);
        const float inv_n = 1.0f / (float)NPIX;
        float mean = S * inv_n;
        float var  = Q * inv_n - mean * mean;
        float a    = gam * rsqrtf(var + 1e-5f);
        sc_a[t] = a;
        sc_b[t] = bet - mean * a;
    }
    __syncthreads();

    // ---- BN + tanh straight from registers -> fp32 out.
#pragma unroll
    for (int h = 0; h < 2; h++)
#pragma unroll
        for (int r = 0; r < 4; r++) {
            int m0  = quad * 4 + r;
            int chl = h * 16 + m0;
            float a  = sc_a[chl];
            float bb = sc_b[chl];
            float* obase = out + ((size_t)b * COUT + cfg * 32 + chl) * IMG
                               + (size_t)row * WH + l15;
#pragma unroll
            for (int g = 0; g < 2; g++) {
                unsigned pk = ypk[h][r][g];
                obase[(2 * g) * 16]     = fast_tanh(fmaf(bf2f((unsigned short)(pk & 0xffffu)), a, bb));
                obase[(2 * g + 1) * 16] = fast_tanh(fmaf(bf2f((unsigned short)(pk >> 16)), a, bb));
            }
        }
}

extern "C" void kernel_launch(void* const* d_in, const int* in_sizes, int n_in,
                              void* d_out, int out_size, void* d_ws, size_t ws_size,
                              hipStream_t stream) {
    const float* x     = (const float*)d_in[0];
    const float* w     = (const float*)d_in[1];
    // d_in[2] = mask: tap positions known analytically (3x3 dilated, centered at 32)
    const float* gamma = (const float*)d_in[3];
    const float* beta  = (const float*)d_in[4];
    float* out = (float*)d_out;

    // transient state in d_ws — no d_out aliasing anywhere
    unsigned short* xT = (unsigned short*)d_ws;             // 2097152 bf16 (4 MB)
    unsigned short* pw = xT + XTELEMS;                      // 27648 bf16
    float* gsum = (float*)(pw + PWELEMS + 32);              // 96 lines
    float* gsq  = gsum + NGRP * PAD;                        // 96 lines
    unsigned* gcnt  = (unsigned*)(gsq + NGRP * PAD);        // 96 lines
    unsigned* ggo   = gcnt + NGRP * PAD;                    // 96 lines
    unsigned* groot = ggo + NGRP * PAD;                     // 1 line

    prep_kernel<<<621, 256, 0, stream>>>(x, w, xT, pw, (unsigned*)gsum);
    conv_bn_kernel<<<NBLK, 256, 0, stream>>>(xT, pw, gsum, gsq, gcnt, ggo, groot,
                                             gamma, beta, out);
}